// Round 1
// baseline (276.975 us; speedup 1.0000x reference)
//
#include <hip/hip_runtime.h>

// Causal SDPA forward, B=2 H=16 S=2048 D=64, fp32 in/out, bf16 MFMA compute.
// Flash-attention structure: per wave 32 q-rows (2x16 MFMA row-tiles), key
// blocks of 32, online softmax in exp2 domain. Mask input ignored (pure causal).

typedef __attribute__((ext_vector_type(8))) short short8;
typedef __attribute__((ext_vector_type(4))) float floatx4;

constexpr int S = 2048;
constexpr int D = 64;
constexpr int BN = 32;
constexpr int KSTR = 72;   // K LDS row stride (bf16 elems): 64 + 8 pad, keeps 16B align
constexpr int VSTR = 40;   // Vt LDS row stride: 32 + 8 pad
constexpr int PSTR = 40;   // P LDS row stride

__device__ inline short f2bf(float x){
    union { float f; unsigned u; } a; a.f = x;
    unsigned r = a.u + 0x7FFFu + ((a.u >> 16) & 1u);  // RTN-even
    return (short)(r >> 16);
}

__device__ inline float fast_exp2(float x){
#if __has_builtin(__builtin_amdgcn_exp2f)
    return __builtin_amdgcn_exp2f(x);
#else
    return exp2f(x);
#endif
}

__global__ __launch_bounds__(256)
void fa_fwd_kernel(const float* __restrict__ Q, const float* __restrict__ K,
                   const float* __restrict__ V, float* __restrict__ Out)
{
    __shared__ short sK[BN * KSTR];      // [key][d] bf16
    __shared__ short sVt[D * VSTR];      // [d][key] bf16 (transposed)
    __shared__ short sP[4][16 * PSTR];   // per-wave P tile [qrow][key]

    const int tid  = threadIdx.x;
    const int wave = tid >> 6;
    const int lane = tid & 63;
    const int l16  = lane & 15;
    const int quad = lane >> 4;

    const int qb = blockIdx.x & 15;      // S/128 = 16 q-blocks
    const int bh = blockIdx.x >> 4;      // B*H = 32
    const int qr0 = qb * 128 + wave * 32;

    const float* Qb = Q + (size_t)bh * S * D;
    const float* Kb = K + (size_t)bh * S * D;
    const float* Vb = V + (size_t)bh * S * D;
    float* Ob = Out + (size_t)bh * S * D;

    // fold 1/sqrt(64) and log2(e) into Q so softmax uses raw exp2
    const float qscale = 0.125f * 1.44269504f;

    // Q a-frags, resident whole kernel: [row-tile][k-tile]
    short8 qa[2][2];
#pragma unroll
    for (int rt = 0; rt < 2; ++rt){
        const float* qp = Qb + (size_t)(qr0 + rt*16 + l16) * D + quad * 8;
#pragma unroll
        for (int kt = 0; kt < 2; ++kt){
            floatx4 f0 = *(const floatx4*)(qp + kt*32);
            floatx4 f1 = *(const floatx4*)(qp + kt*32 + 4);
            short8 v;
            v[0]=f2bf(f0.x*qscale); v[1]=f2bf(f0.y*qscale);
            v[2]=f2bf(f0.z*qscale); v[3]=f2bf(f0.w*qscale);
            v[4]=f2bf(f1.x*qscale); v[5]=f2bf(f1.y*qscale);
            v[6]=f2bf(f1.z*qscale); v[7]=f2bf(f1.w*qscale);
            qa[rt][kt] = v;
        }
    }

    float m[2][4], lsum[2][4];
    floatx4 Oacc[2][4];
#pragma unroll
    for (int rt = 0; rt < 2; ++rt)
#pragma unroll
        for (int r = 0; r < 4; ++r){ m[rt][r] = -1e30f; lsum[rt][r] = 0.0f; }
#pragma unroll
    for (int rt = 0; rt < 2; ++rt)
#pragma unroll
        for (int t = 0; t < 4; ++t) Oacc[rt][t] = (floatx4){0.f,0.f,0.f,0.f};

    // staging maps (256 threads)
    const int kr = tid >> 3;          // K: key row 0..31
    const int kc = (tid & 7) * 8;     // K: d base
    const int vr = tid & 31;          // V: key row 0..31
    const int vc = (tid >> 5) * 8;    // V: d base
    const float* kSrc = Kb + (size_t)kr * D + kc;
    const float* vSrc = Vb + (size_t)vr * D + vc;

    const int nkb = qb * 4 + 4;       // key blocks to cover rows .. qb*128+127
    for (int kb = 0; kb < nkb; ++kb){
        const int n0 = kb * BN;
        __syncthreads();              // prior iteration's LDS reads done
        {   // stage K tile -> bf16 LDS, one ds_write_b128 per thread
            const float* src = kSrc + (size_t)n0 * D;
            floatx4 f0 = *(const floatx4*)src;
            floatx4 f1 = *(const floatx4*)(src + 4);
            short8 v;
            v[0]=f2bf(f0.x); v[1]=f2bf(f0.y); v[2]=f2bf(f0.z); v[3]=f2bf(f0.w);
            v[4]=f2bf(f1.x); v[5]=f2bf(f1.y); v[6]=f2bf(f1.z); v[7]=f2bf(f1.w);
            *(short8*)&sK[kr * KSTR + kc] = v;
        }
        {   // stage V transposed -> Vt[d][key]
            const float* src = vSrc + (size_t)n0 * D;
            floatx4 f0 = *(const floatx4*)src;
            floatx4 f1 = *(const floatx4*)(src + 4);
            float vals[8] = {f0.x,f0.y,f0.z,f0.w,f1.x,f1.y,f1.z,f1.w};
#pragma unroll
            for (int j = 0; j < 8; ++j)
                sVt[(vc + j) * VSTR + vr] = f2bf(vals[j]);
        }
        __syncthreads();

        if (n0 > qr0 + 31) continue;  // wave fully past diagonal (barriers kept uniform)

        // K b-frags: B[k][n] = K[n][k] -> read K row (nt*16+l16), 8 contig bf16
        short8 kf[2][2];
#pragma unroll
        for (int nt = 0; nt < 2; ++nt)
#pragma unroll
            for (int kt = 0; kt < 2; ++kt)
                kf[nt][kt] = *(const short8*)&sK[(nt*16 + l16) * KSTR + kt*32 + quad*8];
        // V b-frags: B[k][n] = V[k][n] -> read Vt row (dt*16+l16), 8 contig keys
        short8 vf[4];
#pragma unroll
        for (int dt = 0; dt < 4; ++dt)
            vf[dt] = *(const short8*)&sVt[(dt*16 + l16) * VSTR + quad*8];

#pragma unroll
        for (int rt = 0; rt < 2; ++rt){
            const int r0 = qr0 + rt * 16;
            if (n0 > r0 + 15) continue;   // this row-tile fully masked

            floatx4 s0 = (floatx4){0.f,0.f,0.f,0.f};
            floatx4 s1 = (floatx4){0.f,0.f,0.f,0.f};
            s0 = __builtin_amdgcn_mfma_f32_16x16x32_bf16(qa[rt][0], kf[0][0], s0, 0,0,0);
            s0 = __builtin_amdgcn_mfma_f32_16x16x32_bf16(qa[rt][1], kf[0][1], s0, 0,0,0);
            s1 = __builtin_amdgcn_mfma_f32_16x16x32_bf16(qa[rt][0], kf[1][0], s1, 0,0,0);
            s1 = __builtin_amdgcn_mfma_f32_16x16x32_bf16(qa[rt][1], kf[1][1], s1, 0,0,0);

            if (n0 + BN - 1 > r0){        // diagonal tile: per-element causal mask
                const int rowb = r0 + quad * 4;
                const int c0 = n0 + l16, c1 = n0 + 16 + l16;
#pragma unroll
                for (int r = 0; r < 4; ++r){
                    s0[r] = (c0 <= rowb + r) ? s0[r] : -1e9f;
                    s1[r] = (c1 <= rowb + r) ? s1[r] : -1e9f;
                }
            }

            // online softmax (base-2 domain). C layout: row = quad*4+r, col = l16.
            float mc[4], al[4], rs[4];
#pragma unroll
            for (int r = 0; r < 4; ++r) mc[r] = fmaxf(s0[r], s1[r]);
#pragma unroll
            for (int off = 8; off >= 1; off >>= 1)
#pragma unroll
                for (int r = 0; r < 4; ++r)
                    mc[r] = fmaxf(mc[r], __shfl_xor(mc[r], off, 64));
#pragma unroll
            for (int r = 0; r < 4; ++r){
                const float mn = fmaxf(m[rt][r], mc[r]);
                al[r] = fast_exp2(m[rt][r] - mn);
                m[rt][r] = mn;
            }
#pragma unroll
            for (int r = 0; r < 4; ++r){
                const float p0 = fast_exp2(s0[r] - m[rt][r]);
                const float p1 = fast_exp2(s1[r] - m[rt][r]);
                rs[r] = p0 + p1;
                sP[wave][(quad*4 + r) * PSTR + l16]      = f2bf(p0);
                sP[wave][(quad*4 + r) * PSTR + 16 + l16] = f2bf(p1);
            }
#pragma unroll
            for (int off = 8; off >= 1; off >>= 1)
#pragma unroll
                for (int r = 0; r < 4; ++r)
                    rs[r] += __shfl_xor(rs[r], off, 64);
#pragma unroll
            for (int r = 0; r < 4; ++r) lsum[rt][r] = lsum[rt][r] * al[r] + rs[r];
#pragma unroll
            for (int t = 0; t < 4; ++t)
#pragma unroll
                for (int r = 0; r < 4; ++r) Oacc[rt][t][r] *= al[r];

            // P: C-layout -> A-layout via per-wave LDS round trip
            asm volatile("s_waitcnt lgkmcnt(0)" ::: "memory");
            const short8 pa = *(const short8*)&sP[wave][l16 * PSTR + quad * 8];
#pragma unroll
            for (int dt = 0; dt < 4; ++dt)
                Oacc[rt][dt] = __builtin_amdgcn_mfma_f32_16x16x32_bf16(pa, vf[dt], Oacc[rt][dt], 0,0,0);
        }
    }

    // epilogue: O / l, C layout -> global fp32
#pragma unroll
    for (int rt = 0; rt < 2; ++rt){
        float inv[4];
#pragma unroll
        for (int r = 0; r < 4; ++r) inv[r] = 1.0f / lsum[rt][r];
        float* op = Ob + (size_t)(qr0 + rt*16 + quad*4) * D + l16;
#pragma unroll
        for (int r = 0; r < 4; ++r)
#pragma unroll
            for (int t = 0; t < 4; ++t)
                op[(size_t)r * D + t*16] = Oacc[rt][t][r] * inv[r];
    }
}

extern "C" void kernel_launch(void* const* d_in, const int* in_sizes, int n_in,
                              void* d_out, int out_size, void* d_ws, size_t ws_size,
                              hipStream_t stream) {
    const float* q = (const float*)d_in[0];
    const float* k = (const float*)d_in[1];
    const float* v = (const float*)d_in[2];
    // d_in[3] = causal_mask: ignored, causality computed analytically.
    float* out = (float*)d_out;
    dim3 grid(512);   // 32 (B*H) * 16 (S/128)
    dim3 block(256);
    hipLaunchKernelGGL(fa_fwd_kernel, grid, block, 0, stream, q, k, v, out);
}

// Round 2
// 198.995 us; speedup vs baseline: 1.3919x; 1.3919x over previous
//
#include <hip/hip_runtime.h>

// Causal SDPA fwd, B=2 H=16 S=2048 D=64, fp32 in/out, bf16 MFMA.
// R2: transposed-score flash attention. Block = 256 thr (4 waves), q-tile =
// 64 rows (16/wave), key-block BN=64, grid = 1024 (4 blocks/CU resident).
// S^T = K*Q^T so softmax reduces in-lane (+2 shuffles); P^T -> PV B-frag via
// ds_bpermute (no LDS round-trip); O accumulated transposed (O^T = V^T P^T).

typedef __attribute__((ext_vector_type(8))) short short8;
typedef __attribute__((ext_vector_type(4))) float floatx4;
typedef __attribute__((ext_vector_type(4))) int intx4;

constexpr int S = 2048;
constexpr int D = 64;
constexpr int KSTR = 72;   // sK row stride (shorts): 64 + 8 pad
constexpr int VSTR = 72;   // sVt row stride (shorts)

__device__ inline short f2bf(float x){                 // RTN-even
    unsigned u = __builtin_bit_cast(unsigned, x);
    unsigned r = u + 0x7FFFu + ((u >> 16) & 1u);
    return (short)(r >> 16);
}
__device__ inline float fast_exp2(float x){ return __builtin_amdgcn_exp2f(x); }

__global__ __launch_bounds__(256, 4)
void fa_fwd_kernel(const float* __restrict__ Q, const float* __restrict__ K,
                   const float* __restrict__ V, float* __restrict__ Out)
{
    __shared__ short sK [64 * KSTR];   // [key][d]  bf16
    __shared__ short sVt[64 * VSTR];   // [d][key]  bf16

    const int tid  = threadIdx.x;
    const int wave = tid >> 6;
    const int lane = tid & 63;
    const int l16  = lane & 15;
    const int quad = lane >> 4;

    // XCD-aware map (xcd ~ blk%8): each XCD works on 4 consecutive bh values
    const unsigned ub = blockIdx.x;
    const int bh = (int)((ub & 7u) * 4u + (ub >> 8));   // 0..31
    const int qt = (int)((ub >> 3) & 31u);              // 0..31 q-tile of 64
    const int r0 = qt * 64 + wave * 16;                 // this wave's 16 q-rows

    const float* Qb = Q + (size_t)bh * S * D;
    const float* Kb = K + (size_t)bh * S * D;
    const float* Vb = V + (size_t)bh * S * D;
    float* Ob = Out + (size_t)bh * S * D;

    const float qscale = 0.125f * 1.44269504f;  // 1/sqrt(64) * log2(e)

    // Q fragment (B-operand of K*Q^T == A-frag contents of Q): resident
    short8 qa[2];
    {
        const float* qp = Qb + (size_t)(r0 + l16) * D + quad * 8;
#pragma unroll
        for (int kt = 0; kt < 2; ++kt){
            floatx4 f0 = *(const floatx4*)(qp + kt*32);
            floatx4 f1 = *(const floatx4*)(qp + kt*32 + 4);
            short8 v;
            v[0]=f2bf(f0.x*qscale); v[1]=f2bf(f0.y*qscale);
            v[2]=f2bf(f0.z*qscale); v[3]=f2bf(f0.w*qscale);
            v[4]=f2bf(f1.x*qscale); v[5]=f2bf(f1.y*qscale);
            v[6]=f2bf(f1.z*qscale); v[7]=f2bf(f1.w*qscale);
            qa[kt] = v;
        }
    }

    float mrow = -1e30f, lsum = 0.0f;          // per qrow (= per l16), lane-scalar
    floatx4 Oacc[4];                           // O^T tiles: [dt], C-layout
#pragma unroll
    for (int dt = 0; dt < 4; ++dt) Oacc[dt] = (floatx4){0.f,0.f,0.f,0.f};

    // staging maps
    const int kr = tid >> 2;            // K: key row 0..63
    const int kc = (tid & 3) * 16;      // K: d base {0,16,32,48}
    const int vk = tid & 63;            // V: key 0..63
    const int vd = (tid >> 6) * 16;     // V: d base {0,16,32,48}

    const int nkb = qt + 1;             // 64-key blocks
    for (int kb = 0; kb < nkb; ++kb){
        const int n0 = kb * 64;
        __syncthreads();
        {   // stage K[n0..n0+63][0..63] -> sK bf16
            const float* src = Kb + (size_t)(n0 + kr) * D + kc;
            floatx4 f0 = *(const floatx4*)(src);
            floatx4 f1 = *(const floatx4*)(src + 4);
            floatx4 f2 = *(const floatx4*)(src + 8);
            floatx4 f3 = *(const floatx4*)(src + 12);
            short8 w0, w1;
            w0[0]=f2bf(f0.x); w0[1]=f2bf(f0.y); w0[2]=f2bf(f0.z); w0[3]=f2bf(f0.w);
            w0[4]=f2bf(f1.x); w0[5]=f2bf(f1.y); w0[6]=f2bf(f1.z); w0[7]=f2bf(f1.w);
            w1[0]=f2bf(f2.x); w1[1]=f2bf(f2.y); w1[2]=f2bf(f2.z); w1[3]=f2bf(f2.w);
            w1[4]=f2bf(f3.x); w1[5]=f2bf(f3.y); w1[6]=f2bf(f3.z); w1[7]=f2bf(f3.w);
            *(short8*)&sK[kr * KSTR + kc]     = w0;
            *(short8*)&sK[kr * KSTR + kc + 8] = w1;
        }
        {   // stage V transposed -> sVt[d][key]
            const float* src = Vb + (size_t)(n0 + vk) * D + vd;
            floatx4 f0 = *(const floatx4*)(src);
            floatx4 f1 = *(const floatx4*)(src + 4);
            floatx4 f2 = *(const floatx4*)(src + 8);
            floatx4 f3 = *(const floatx4*)(src + 12);
            float vals[16] = {f0.x,f0.y,f0.z,f0.w, f1.x,f1.y,f1.z,f1.w,
                              f2.x,f2.y,f2.z,f2.w, f3.x,f3.y,f3.z,f3.w};
#pragma unroll
            for (int j = 0; j < 16; ++j)
                sVt[(vd + j) * VSTR + vk] = f2bf(vals[j]);
        }
        __syncthreads();

        // active key tiles for this wave: t*16 <= r0+15-n0
        const int lastT = min(3, (r0 + 15 - n0) >> 4);

        // --- S^T = K_tile * Q^T ; C layout: row=key(quad*4+r), col=qrow(l16)
        float p[4][4];
#pragma unroll
        for (int t = 0; t < 4; ++t)
#pragma unroll
            for (int r = 0; r < 4; ++r) p[t][r] = 0.0f;

        float mx = -1e30f;
#pragma unroll
        for (int t = 0; t < 4; ++t){
            if (t > lastT) continue;
            const short8 kf0 = *(const short8*)&sK[(t*16 + l16) * KSTR + quad*8];
            const short8 kf1 = *(const short8*)&sK[(t*16 + l16) * KSTR + 32 + quad*8];
            floatx4 acc = (floatx4){0.f,0.f,0.f,0.f};
            acc = __builtin_amdgcn_mfma_f32_16x16x32_bf16(kf0, qa[0], acc, 0,0,0);
            acc = __builtin_amdgcn_mfma_f32_16x16x32_bf16(kf1, qa[1], acc, 0,0,0);
            if (n0 + t*16 + 15 > r0){              // diagonal tile: mask key>qrow
                const int keyb = n0 + t*16 + quad*4;
                const int qrow = r0 + l16;
#pragma unroll
                for (int r = 0; r < 4; ++r)
                    acc[r] = (keyb + r <= qrow) ? acc[r] : -1e9f;
            }
#pragma unroll
            for (int r = 0; r < 4; ++r){ p[t][r] = acc[r]; mx = fmaxf(mx, acc[r]); }
        }
        // column (qrow) max: in-lane done, reduce across quads only
        mx = fmaxf(mx, __shfl_xor(mx, 16, 64));
        mx = fmaxf(mx, __shfl_xor(mx, 32, 64));

        const float mn = fmaxf(mrow, mx);
        const float al = fast_exp2(mrow - mn);
        mrow = mn;

        float rs = 0.0f;
#pragma unroll
        for (int t = 0; t < 4; ++t){
            if (t > lastT) continue;
#pragma unroll
            for (int r = 0; r < 4; ++r){
                p[t][r] = fast_exp2(p[t][r] - mn);
                rs += p[t][r];
            }
        }
        rs += __shfl_xor(rs, 16, 64);
        rs += __shfl_xor(rs, 32, 64);
        lsum = lsum * al + rs;
#pragma unroll
        for (int dt = 0; dt < 4; ++dt)
#pragma unroll
            for (int r = 0; r < 4; ++r) Oacc[dt][r] *= al;

        // pack P^T to bf16 pairs (truncate): pk[t][h] = [p(2h+1) : p(2h)]
        unsigned pk[4][2];
#pragma unroll
        for (int t = 0; t < 4; ++t)
#pragma unroll
            for (int h = 0; h < 2; ++h){
                unsigned lo = __builtin_bit_cast(unsigned, p[t][2*h]);
                unsigned hi = __builtin_bit_cast(unsigned, p[t][2*h+1]);
                pk[t][h] = (lo >> 16) | (hi & 0xFFFF0000u);
            }

        // PV: O^T += V^T * P^T, per 32-key chunk. B-frag of P^T via bpermute.
        const int addr_lo = (l16 + ((quad & 1) << 5)) << 2;
        const int addr_hi = addr_lo + 64;
        const bool hiQ = quad >= 2;
#pragma unroll
        for (int c = 0; c < 2; ++c){
            if (2*c > lastT) continue;
            const int ta = 2*c, tb = 2*c + 1;
            int a0 = __builtin_amdgcn_ds_bpermute(addr_lo, (int)pk[ta][0]);
            int b0 = __builtin_amdgcn_ds_bpermute(addr_lo, (int)pk[tb][0]);
            int a1 = __builtin_amdgcn_ds_bpermute(addr_lo, (int)pk[ta][1]);
            int b1 = __builtin_amdgcn_ds_bpermute(addr_lo, (int)pk[tb][1]);
            int a2 = __builtin_amdgcn_ds_bpermute(addr_hi, (int)pk[ta][0]);
            int b2 = __builtin_amdgcn_ds_bpermute(addr_hi, (int)pk[tb][0]);
            int a3 = __builtin_amdgcn_ds_bpermute(addr_hi, (int)pk[ta][1]);
            int b3 = __builtin_amdgcn_ds_bpermute(addr_hi, (int)pk[tb][1]);
            union { intx4 i4; short8 s8; } bf;
            bf.i4[0] = hiQ ? b0 : a0;
            bf.i4[1] = hiQ ? b1 : a1;
            bf.i4[2] = hiQ ? b2 : a2;
            bf.i4[3] = hiQ ? b3 : a3;
#pragma unroll
            for (int dt = 0; dt < 4; ++dt){
                const short8 vf = *(const short8*)&sVt[(dt*16 + l16) * VSTR + c*32 + quad*8];
                Oacc[dt] = __builtin_amdgcn_mfma_f32_16x16x32_bf16(vf, bf.s8, Oacc[dt], 0,0,0);
            }
        }
    }

    // epilogue: O[qrow][d] = O^T / lsum. C-layout: row=d_local, col=qrow.
    const float inv = 1.0f / lsum;
    float* op = Ob + (size_t)(r0 + l16) * D + quad * 4;
#pragma unroll
    for (int dt = 0; dt < 4; ++dt){
        floatx4 o;
#pragma unroll
        for (int r = 0; r < 4; ++r) o[r] = Oacc[dt][r] * inv;
        *(floatx4*)(op + dt*16) = o;
    }
}

extern "C" void kernel_launch(void* const* d_in, const int* in_sizes, int n_in,
                              void* d_out, int out_size, void* d_ws, size_t ws_size,
                              hipStream_t stream) {
    const float* q = (const float*)d_in[0];
    const float* k = (const float*)d_in[1];
    const float* v = (const float*)d_in[2];
    // d_in[3] = causal_mask: ignored (causality computed analytically)
    float* out = (float*)d_out;
    dim3 grid(1024);   // 32 bh * 32 q-tiles of 64 rows
    dim3 block(256);
    hipLaunchKernelGGL(fa_fwd_kernel, grid, block, 0, stream, q, k, v, out);
}

// Round 3
// 154.563 us; speedup vs baseline: 1.7920x; 1.2875x over previous
//
#include <hip/hip_runtime.h>

// Causal SDPA fwd, B=2 H=16 S=2048 D=64, fp32 in/out, bf16 MFMA.
// R3: balanced pairing (each block does q-tiles qt and 31-qt: exactly 33
// key-iterations/block), register-prefetch software pipeline, double-buffered
// LDS (1 barrier/iter), 4x4-transpose V staging (ds_write_b64).
// S^T = K*Q^T (softmax reduces in-lane + 2 shuffles); P^T -> PV B-frag via
// ds_bpermute; O accumulated transposed (O^T = V^T P^T).

typedef __attribute__((ext_vector_type(8))) short short8;
typedef __attribute__((ext_vector_type(4))) short short4v;
typedef __attribute__((ext_vector_type(4))) float floatx4;
typedef __attribute__((ext_vector_type(4))) int intx4;

constexpr int S = 2048;
constexpr int D = 64;
constexpr int KSTR = 72;   // sK row stride (shorts): 64 + 8 pad
constexpr int VSTR = 72;   // sVt row stride (shorts)

__device__ inline short f2bf(float x){                 // RTN-even
    unsigned u = __builtin_bit_cast(unsigned, x);
    unsigned r = u + 0x7FFFu + ((u >> 16) & 1u);
    return (short)(r >> 16);
}
__device__ inline float fast_exp2(float x){ return __builtin_amdgcn_exp2f(x); }

__global__ __launch_bounds__(256, 2)
void fa_fwd_kernel(const float* __restrict__ Q, const float* __restrict__ K,
                   const float* __restrict__ V, float* __restrict__ Out)
{
    __shared__ short sK [2][64 * KSTR];   // [buf][key][d]  bf16
    __shared__ short sVt[2][64 * VSTR];   // [buf][d][key]  bf16

    const int tid  = threadIdx.x;
    const int wave = tid >> 6;
    const int lane = tid & 63;
    const int l16  = lane & 15;
    const int quad = lane >> 4;

    // grid 512 = xcd(8) x pair(16) x bhsub(4); each XCD sees 4 heads (4MB K+V -> its L2)
    const unsigned ub = blockIdx.x;
    const int bh = (int)((ub & 7u) * 4u + (ub >> 7));   // 0..31
    const int qp = (int)((ub >> 3) & 15u);              // pair index 0..15

    const float* Qb = Q + (size_t)bh * S * D;
    const float* Kb = K + (size_t)bh * S * D;
    const float* Vb = V + (size_t)bh * S * D;
    float* Ob = Out + (size_t)bh * S * D;

    const float qscale = 0.125f * 1.44269504f;  // 1/sqrt(64) * log2(e)

    // staging maps
    const int kr = tid >> 2;              // K: key row 0..63
    const int kc = (tid & 3) * 16;        // K: d base {0,16,32,48}
    const int vd0   = (tid & 15) * 4;     // V: d base (4-wide)
    const int vkey0 = (tid >> 4) * 4;     // V: key base (4-wide)
    const float* kSrc = Kb + (size_t)kr * D + kc;
    const float* vSrc = Vb + (size_t)vkey0 * D + vd0;

    // prefetch registers; preload tile n0=0
    floatx4 kpre[4], vpre[4];
#pragma unroll
    for (int i = 0; i < 4; ++i) kpre[i] = *(const floatx4*)(kSrc + i*4);
#pragma unroll
    for (int r = 0; r < 4; ++r) vpre[r] = *(const floatx4*)(vSrc + (size_t)r*D);

    int pb = 0;   // LDS buffer parity, toggles every flat iteration
#pragma unroll 1
    for (int seg = 0; seg < 2; ++seg){
        const int qt  = seg ? (31 - qp) : qp;   // work (qt+1); pair sum = 33
        const int nkb = qt + 1;
        const int r0  = qt * 64 + wave * 16;    // this wave's 16 q-rows

        // Q fragment (B-operand of K*Q^T): resident for the segment
        short8 qa[2];
        {
            const float* qptr = Qb + (size_t)(r0 + l16) * D + quad * 8;
#pragma unroll
            for (int kt = 0; kt < 2; ++kt){
                floatx4 f0 = *(const floatx4*)(qptr + kt*32);
                floatx4 f1 = *(const floatx4*)(qptr + kt*32 + 4);
                short8 v;
                v[0]=f2bf(f0.x*qscale); v[1]=f2bf(f0.y*qscale);
                v[2]=f2bf(f0.z*qscale); v[3]=f2bf(f0.w*qscale);
                v[4]=f2bf(f1.x*qscale); v[5]=f2bf(f1.y*qscale);
                v[6]=f2bf(f1.z*qscale); v[7]=f2bf(f1.w*qscale);
                qa[kt] = v;
            }
        }

        float mrow = -1e30f, lsum = 0.0f;      // per qrow (= per l16)
        floatx4 Oacc[4];                       // O^T tiles [dt], C-layout
#pragma unroll
        for (int dt = 0; dt < 4; ++dt) Oacc[dt] = (floatx4){0.f,0.f,0.f,0.f};

#pragma unroll 1
        for (int kb = 0; kb < nkb; ++kb){
            const int n0 = kb * 64;

            // --- drain prefetch regs (vmcnt wait lands here) -> LDS buf pb
            {
                short8 w0, w1;
                w0[0]=f2bf(kpre[0].x); w0[1]=f2bf(kpre[0].y); w0[2]=f2bf(kpre[0].z); w0[3]=f2bf(kpre[0].w);
                w0[4]=f2bf(kpre[1].x); w0[5]=f2bf(kpre[1].y); w0[6]=f2bf(kpre[1].z); w0[7]=f2bf(kpre[1].w);
                w1[0]=f2bf(kpre[2].x); w1[1]=f2bf(kpre[2].y); w1[2]=f2bf(kpre[2].z); w1[3]=f2bf(kpre[2].w);
                w1[4]=f2bf(kpre[3].x); w1[5]=f2bf(kpre[3].y); w1[6]=f2bf(kpre[3].z); w1[7]=f2bf(kpre[3].w);
                *(short8*)&sK[pb][kr * KSTR + kc]     = w0;
                *(short8*)&sK[pb][kr * KSTR + kc + 8] = w1;
#pragma unroll
                for (int j = 0; j < 4; ++j){
                    short4v sj;
                    sj[0]=f2bf(vpre[0][j]); sj[1]=f2bf(vpre[1][j]);
                    sj[2]=f2bf(vpre[2][j]); sj[3]=f2bf(vpre[3][j]);
                    *(short4v*)&sVt[pb][(vd0 + j) * VSTR + vkey0] = sj;
                }
            }

            // --- issue next-tile prefetch (consumed next iteration)
            {
                const int n0n = (kb + 1 < nkb) ? (n0 + 64) : 0;  // next seg starts at 0
                const float* ks = kSrc + (size_t)n0n * D;
                const float* vs = vSrc + (size_t)n0n * D;
#pragma unroll
                for (int i = 0; i < 4; ++i) kpre[i] = *(const floatx4*)(ks + i*4);
#pragma unroll
                for (int r = 0; r < 4; ++r) vpre[r] = *(const floatx4*)(vs + (size_t)r*D);
            }

            __syncthreads();   // buf pb ready for all; single barrier per iter

            // active 16-key tiles for this wave: t*16 <= r0+15-n0  (always >=0)
            const int lastT = min(3, (r0 + 15 - n0) >> 4);

            // --- S^T = K_tile * Q^T ; C layout: row=key(quad*4+r), col=qrow(l16)
            float p[4][4];
#pragma unroll
            for (int t = 0; t < 4; ++t)
#pragma unroll
                for (int r = 0; r < 4; ++r) p[t][r] = 0.0f;

            float mx = -1e30f;
#pragma unroll
            for (int t = 0; t < 4; ++t){
                if (t > lastT) continue;
                const short8 kf0 = *(const short8*)&sK[pb][(t*16 + l16) * KSTR + quad*8];
                const short8 kf1 = *(const short8*)&sK[pb][(t*16 + l16) * KSTR + 32 + quad*8];
                floatx4 acc = (floatx4){0.f,0.f,0.f,0.f};
                acc = __builtin_amdgcn_mfma_f32_16x16x32_bf16(kf0, qa[0], acc, 0,0,0);
                acc = __builtin_amdgcn_mfma_f32_16x16x32_bf16(kf1, qa[1], acc, 0,0,0);
                if (n0 + t*16 + 15 > r0){          // diagonal tile: mask key>qrow
                    const int keyb = n0 + t*16 + quad*4;
                    const int qrow = r0 + l16;
#pragma unroll
                    for (int r = 0; r < 4; ++r)
                        acc[r] = (keyb + r <= qrow) ? acc[r] : -1e9f;
                }
#pragma unroll
                for (int r = 0; r < 4; ++r){ p[t][r] = acc[r]; mx = fmaxf(mx, acc[r]); }
            }
            mx = fmaxf(mx, __shfl_xor(mx, 16, 64));
            mx = fmaxf(mx, __shfl_xor(mx, 32, 64));

            const float mn = fmaxf(mrow, mx);
            const float al = fast_exp2(mrow - mn);
            mrow = mn;

            float rs = 0.0f;
#pragma unroll
            for (int t = 0; t < 4; ++t){
                if (t > lastT) continue;
#pragma unroll
                for (int r = 0; r < 4; ++r){
                    p[t][r] = fast_exp2(p[t][r] - mn);
                    rs += p[t][r];
                }
            }
            rs += __shfl_xor(rs, 16, 64);
            rs += __shfl_xor(rs, 32, 64);
            lsum = lsum * al + rs;
#pragma unroll
            for (int dt = 0; dt < 4; ++dt)
#pragma unroll
                for (int r = 0; r < 4; ++r) Oacc[dt][r] *= al;

            // pack P^T to bf16 pairs (truncate): pk[t][h] = [p(2h+1) : p(2h)]
            unsigned pk[4][2];
#pragma unroll
            for (int t = 0; t < 4; ++t)
#pragma unroll
                for (int h = 0; h < 2; ++h){
                    unsigned lo = __builtin_bit_cast(unsigned, p[t][2*h]);
                    unsigned hi = __builtin_bit_cast(unsigned, p[t][2*h+1]);
                    pk[t][h] = (lo >> 16) | (hi & 0xFFFF0000u);
                }

            // PV: O^T += V^T * P^T, per 32-key chunk; P^T B-frag via bpermute
            const int addr_lo = (l16 + ((quad & 1) << 5)) << 2;
            const int addr_hi = addr_lo + 64;
            const bool hiQ = quad >= 2;
#pragma unroll
            for (int c = 0; c < 2; ++c){
                if (2*c > lastT) continue;
                const int ta = 2*c, tb = 2*c + 1;
                int a0 = __builtin_amdgcn_ds_bpermute(addr_lo, (int)pk[ta][0]);
                int b0 = __builtin_amdgcn_ds_bpermute(addr_lo, (int)pk[tb][0]);
                int a1 = __builtin_amdgcn_ds_bpermute(addr_lo, (int)pk[ta][1]);
                int b1 = __builtin_amdgcn_ds_bpermute(addr_lo, (int)pk[tb][1]);
                int a2 = __builtin_amdgcn_ds_bpermute(addr_hi, (int)pk[ta][0]);
                int b2 = __builtin_amdgcn_ds_bpermute(addr_hi, (int)pk[tb][0]);
                int a3 = __builtin_amdgcn_ds_bpermute(addr_hi, (int)pk[ta][1]);
                int b3 = __builtin_amdgcn_ds_bpermute(addr_hi, (int)pk[tb][1]);
                union { intx4 i4; short8 s8; } bf;
                bf.i4[0] = hiQ ? b0 : a0;
                bf.i4[1] = hiQ ? b1 : a1;
                bf.i4[2] = hiQ ? b2 : a2;
                bf.i4[3] = hiQ ? b3 : a3;
#pragma unroll
                for (int dt = 0; dt < 4; ++dt){
                    const short8 vf = *(const short8*)&sVt[pb][(dt*16 + l16) * VSTR + c*32 + quad*8];
                    Oacc[dt] = __builtin_amdgcn_mfma_f32_16x16x32_bf16(vf, bf.s8, Oacc[dt], 0,0,0);
                }
            }
            pb ^= 1;
        }

        // epilogue: O[qrow][d] = O^T / lsum. C-layout: row=d_local, col=qrow.
        const float inv = 1.0f / lsum;
        float* op = Ob + (size_t)(r0 + l16) * D + quad * 4;
#pragma unroll
        for (int dt = 0; dt < 4; ++dt){
            floatx4 o;
#pragma unroll
            for (int r = 0; r < 4; ++r) o[r] = Oacc[dt][r] * inv;
            *(floatx4*)(op + dt*16) = o;
        }
    }
}

extern "C" void kernel_launch(void* const* d_in, const int* in_sizes, int n_in,
                              void* d_out, int out_size, void* d_ws, size_t ws_size,
                              hipStream_t stream) {
    const float* q = (const float*)d_in[0];
    const float* k = (const float*)d_in[1];
    const float* v = (const float*)d_in[2];
    // d_in[3] = causal_mask: ignored (causality computed analytically)
    float* out = (float*)d_out;
    dim3 grid(512);    // 8 xcd * 16 pairs * 4 bhsub
    dim3 block(256);
    hipLaunchKernelGGL(fa_fwd_kernel, grid, block, 0, stream, q, k, v, out);
}

// Round 5
// 145.872 us; speedup vs baseline: 1.8988x; 1.0596x over previous
//
#include <hip/hip_runtime.h>

// Causal SDPA fwd, B=2 H=16 S=2048 D=64, fp32 in/out, bf16 MFMA.
// R5: prepass packs K and V^T to bf16 MFMA-fragment order in d_ws. Main
// kernel stages fragments via plain global loads -> VGPR -> ds_write_b128
// lane-linear (conflict-free, no conversion VALU, no async-DMA race).
// Grid 1024: one 64-row q-tile/block, longest-first dispatch, XCD swizzle.
// S^T = K*Q^T (in-lane softmax + 2 shuffles); P^T -> PV B-frag via
// ds_bpermute; O accumulated transposed (O^T = V^T P^T).

typedef __attribute__((ext_vector_type(8))) short short8;
typedef __attribute__((ext_vector_type(4))) short short4v;
typedef __attribute__((ext_vector_type(4))) float floatx4;
typedef __attribute__((ext_vector_type(4))) int intx4;

constexpr int S = 2048;
constexpr int D = 64;
constexpr size_t TILE_SH = 8 * 64 * 8;             // shorts per 64-key tile (8 frags)
constexpr size_t TENSOR_SH = 32ull * 32 * TILE_SH; // per K or V: 32 bh * 32 tiles
constexpr size_t WS_NEEDED = 2 * TENSOR_SH * 2;    // bytes = 16 MB

__device__ inline short f2bf(float x){                 // RTN-even
    unsigned u = __builtin_bit_cast(unsigned, x);
    unsigned r = u + 0x7FFFu + ((u >> 16) & 1u);
    return (short)(r >> 16);
}
__device__ inline float fast_exp2(float x){ return __builtin_amdgcn_exp2f(x); }

// ---------- prepass: K, V -> bf16 fragment-ordered scratch ----------
// K frag f=t*2+kt, elem j: K[kb*64 + t*16 + (lane&15)][kt*32 + (lane>>4)*8 + j]
// V frag f=c*4+dt, elem j: V[kb*64 + c*32 + (lane>>4)*8 + j][dt*16 + (lane&15)]
__global__ __launch_bounds__(256)
void prepack_kernel(const float* __restrict__ K, const float* __restrict__ V,
                    short* __restrict__ Kf, short* __restrict__ Vf)
{
    const int blk = blockIdx.x;
    const int bh = blk >> 5, kb = blk & 31;
    const int tid = threadIdx.x;
    const float* Kb = K + (size_t)bh * S * D + (size_t)kb * 64 * D;
    const float* Vb = V + (size_t)bh * S * D + (size_t)kb * 64 * D;
    short* Kfb = Kf + (size_t)(bh * 32 + kb) * TILE_SH;
    short* Vfb = Vf + (size_t)(bh * 32 + kb) * TILE_SH;
#pragma unroll
    for (int h = 0; h < 2; ++h){
        const int s = tid + h * 256;           // frag slot: f = s>>6, lane = s&63
        const int f = s >> 6, lane = s & 63;
        const int l16 = lane & 15, quad = lane >> 4;
        {   // K fragment
            const int t = f >> 1, kt = f & 1;
            const float* src = Kb + (size_t)(t*16 + l16) * D + kt*32 + quad*8;
            floatx4 a = *(const floatx4*)src;
            floatx4 b = *(const floatx4*)(src + 4);
            short8 v;
            v[0]=f2bf(a.x); v[1]=f2bf(a.y); v[2]=f2bf(a.z); v[3]=f2bf(a.w);
            v[4]=f2bf(b.x); v[5]=f2bf(b.y); v[6]=f2bf(b.z); v[7]=f2bf(b.w);
            *(short8*)&Kfb[(size_t)s * 8] = v;
        }
        {   // V^T fragment
            const int c = f >> 2, dt = f & 3;
            const int d = dt*16 + l16, key0 = c*32 + quad*8;
            short8 v;
#pragma unroll
            for (int j = 0; j < 8; ++j)
                v[j] = f2bf(Vb[(size_t)(key0 + j) * D + d]);
            *(short8*)&Vfb[(size_t)s * 8] = v;
        }
    }
}

// ---------- main flash kernel ----------
__global__ __launch_bounds__(256, 4)
void fa_fwd_kernel(const float* __restrict__ Q, const short* __restrict__ Kf,
                   const short* __restrict__ Vf, float* __restrict__ Out)
{
    __shared__ short sF[2][16 * 512];   // [buf][frag slot 0-7=K, 8-15=V][lane*8]

    const int tid  = threadIdx.x;
    const int wave = tid >> 6;
    const int lane = tid & 63;
    const int l16  = lane & 15;
    const int quad = lane >> 4;

    // grid 1024 = xcd(8) x i(128); bh = xcd*4 + (i&3) (4 heads/XCD for L2),
    // qt = 31 - (i>>2): longest q-tiles dispatched first (load balance).
    const unsigned ub = blockIdx.x;
    const int i  = (int)(ub >> 3);
    const int bh = (int)(ub & 7u) * 4 + (i & 3);
    const int qt = 31 - (i >> 2);
    const int r0 = qt * 64 + wave * 16;
    const int nkb = qt + 1;

    const float* Qb = Q + (size_t)bh * S * D;
    const short* Kfb = Kf + (size_t)bh * 32 * TILE_SH;
    const short* Vfb = Vf + (size_t)bh * 32 * TILE_SH;
    float* Ob = Out + (size_t)bh * S * D;

    const float qscale = 0.125f * 1.44269504f;  // 1/sqrt(64) * log2(e)

    // Q fragment (B-operand of K*Q^T), resident
    short8 qa[2];
    {
        const float* qptr = Qb + (size_t)(r0 + l16) * D + quad * 8;
#pragma unroll
        for (int kt = 0; kt < 2; ++kt){
            floatx4 f0 = *(const floatx4*)(qptr + kt*32);
            floatx4 f1 = *(const floatx4*)(qptr + kt*32 + 4);
            short8 v;
            v[0]=f2bf(f0.x*qscale); v[1]=f2bf(f0.y*qscale);
            v[2]=f2bf(f0.z*qscale); v[3]=f2bf(f0.w*qscale);
            v[4]=f2bf(f1.x*qscale); v[5]=f2bf(f1.y*qscale);
            v[6]=f2bf(f1.z*qscale); v[7]=f2bf(f1.w*qscale);
            qa[kt] = v;
        }
    }

    float mrow = -1e30f, lsum = 0.0f;      // per qrow (= per l16)
    floatx4 Oacc[4];                       // O^T tiles [dt], C-layout
#pragma unroll
    for (int dt = 0; dt < 4; ++dt) Oacc[dt] = (floatx4){0.f,0.f,0.f,0.f};

    // wave stages frag slots {4w..4w+3}; slot<8 -> K frag, else V frag
    intx4 pre[4];
    auto prefetch = [&](int kb){
#pragma unroll
        for (int u = 0; u < 4; ++u){
            const int sl = wave * 4 + u;
            const short* src = (sl < 8)
                ? Kfb + (size_t)kb * TILE_SH + (size_t)(sl * 64 + lane) * 8
                : Vfb + (size_t)kb * TILE_SH + (size_t)((sl - 8) * 64 + lane) * 8;
            pre[u] = *(const intx4*)src;
        }
    };

    prefetch(0);
    int pb = 0;

#pragma unroll 1
    for (int kb = 0; kb < nkb; ++kb){
        const int n0 = kb * 64;
        // drain prefetch regs -> LDS buf pb (lane-linear ds_write_b128)
#pragma unroll
        for (int u = 0; u < 4; ++u)
            *(intx4*)&sF[pb][(wave * 4 + u) * 512 + lane * 8] = pre[u];
        prefetch(kb + 1 < nkb ? kb + 1 : 0);   // next tile (or dummy tile 0)
        __syncthreads();                       // buf pb ready for all waves

        const short* fb = &sF[pb][0];
        const int lastT = min(3, (r0 + 15 - n0) >> 4);

        // S^T = K_tile * Q^T ; C layout: row=key(quad*4+r), col=qrow(l16)
        float p[4][4];
        float mx = -1e30f;
#pragma unroll
        for (int t = 0; t < 4; ++t){
#pragma unroll
            for (int r = 0; r < 4; ++r) p[t][r] = 0.0f;
            if (t > lastT) continue;
            const short8 kf0 = *(const short8*)&fb[(t*2    ) * 512 + lane*8];
            const short8 kf1 = *(const short8*)&fb[(t*2 + 1) * 512 + lane*8];
            floatx4 acc = (floatx4){0.f,0.f,0.f,0.f};
            acc = __builtin_amdgcn_mfma_f32_16x16x32_bf16(kf0, qa[0], acc, 0,0,0);
            acc = __builtin_amdgcn_mfma_f32_16x16x32_bf16(kf1, qa[1], acc, 0,0,0);
            if (n0 + t*16 + 15 > r0){          // diagonal tile: mask key>qrow
                const int keyb = n0 + t*16 + quad*4;
                const int qrow = r0 + l16;
#pragma unroll
                for (int r = 0; r < 4; ++r)
                    acc[r] = (keyb + r <= qrow) ? acc[r] : -1e9f;
            }
#pragma unroll
            for (int r = 0; r < 4; ++r){ p[t][r] = acc[r]; mx = fmaxf(mx, acc[r]); }
        }
        mx = fmaxf(mx, __shfl_xor(mx, 16, 64));
        mx = fmaxf(mx, __shfl_xor(mx, 32, 64));

        const float mn = fmaxf(mrow, mx);
        const float al = fast_exp2(mrow - mn);
        mrow = mn;

        float rs = 0.0f;
#pragma unroll
        for (int t = 0; t < 4; ++t){
            if (t > lastT) continue;
#pragma unroll
            for (int r = 0; r < 4; ++r){
                p[t][r] = fast_exp2(p[t][r] - mn);
                rs += p[t][r];
            }
        }
        rs += __shfl_xor(rs, 16, 64);
        rs += __shfl_xor(rs, 32, 64);
        lsum = lsum * al + rs;
#pragma unroll
        for (int dt = 0; dt < 4; ++dt)
#pragma unroll
            for (int r = 0; r < 4; ++r) Oacc[dt][r] *= al;

        // pack P^T to bf16 pairs (truncate)
        unsigned pk[4][2];
#pragma unroll
        for (int t = 0; t < 4; ++t)
#pragma unroll
            for (int h = 0; h < 2; ++h){
                unsigned lo = __builtin_bit_cast(unsigned, p[t][2*h]);
                unsigned hi = __builtin_bit_cast(unsigned, p[t][2*h+1]);
                pk[t][h] = (lo >> 16) | (hi & 0xFFFF0000u);
            }

        // PV: O^T += V^T * P^T ; P^T B-frag via bpermute
        const int addr_lo = (l16 + ((quad & 1) << 5)) << 2;
        const int addr_hi = addr_lo + 64;
        const bool hiQ = quad >= 2;
#pragma unroll
        for (int c = 0; c < 2; ++c){
            if (2*c > lastT) continue;
            const int ta = 2*c, tb = 2*c + 1;
            int a0 = __builtin_amdgcn_ds_bpermute(addr_lo, (int)pk[ta][0]);
            int b0 = __builtin_amdgcn_ds_bpermute(addr_lo, (int)pk[tb][0]);
            int a1 = __builtin_amdgcn_ds_bpermute(addr_lo, (int)pk[ta][1]);
            int b1 = __builtin_amdgcn_ds_bpermute(addr_lo, (int)pk[tb][1]);
            int a2 = __builtin_amdgcn_ds_bpermute(addr_hi, (int)pk[ta][0]);
            int b2 = __builtin_amdgcn_ds_bpermute(addr_hi, (int)pk[tb][0]);
            int a3 = __builtin_amdgcn_ds_bpermute(addr_hi, (int)pk[ta][1]);
            int b3 = __builtin_amdgcn_ds_bpermute(addr_hi, (int)pk[tb][1]);
            union { intx4 i4; short8 s8; } bf;
            bf.i4[0] = hiQ ? b0 : a0;
            bf.i4[1] = hiQ ? b1 : a1;
            bf.i4[2] = hiQ ? b2 : a2;
            bf.i4[3] = hiQ ? b3 : a3;
#pragma unroll
            for (int dt = 0; dt < 4; ++dt){
                const short8 vf = *(const short8*)&fb[(8 + c*4 + dt) * 512 + lane*8];
                Oacc[dt] = __builtin_amdgcn_mfma_f32_16x16x32_bf16(vf, bf.s8, Oacc[dt], 0,0,0);
            }
        }
        pb ^= 1;
    }

    // epilogue: O[qrow][d] = O^T / lsum. C-layout: row=d_local, col=qrow.
    const float inv = 1.0f / lsum;
    float* op = Ob + (size_t)(r0 + l16) * D + quad * 4;
#pragma unroll
    for (int dt = 0; dt < 4; ++dt){
        floatx4 o;
#pragma unroll
        for (int r = 0; r < 4; ++r) o[r] = Oacc[dt][r] * inv;
        *(floatx4*)(op + dt*16) = o;
    }
}

// ---------- fallback (R3 kernel) if ws too small ----------
constexpr int KSTR = 72;
constexpr int VSTR = 72;
__global__ __launch_bounds__(256, 2)
void fa_fwd_fallback(const float* __restrict__ Q, const float* __restrict__ K,
                     const float* __restrict__ V, float* __restrict__ Out)
{
    __shared__ short sK [2][64 * KSTR];
    __shared__ short sVt[2][64 * VSTR];
    const int tid  = threadIdx.x;
    const int wave = tid >> 6;
    const int lane = tid & 63;
    const int l16  = lane & 15;
    const int quad = lane >> 4;
    const unsigned ub = blockIdx.x;
    const int bh = (int)((ub & 7u) * 4u + (ub >> 7));
    const int qp = (int)((ub >> 3) & 15u);
    const float* Qb = Q + (size_t)bh * S * D;
    const float* Kb = K + (size_t)bh * S * D;
    const float* Vb = V + (size_t)bh * S * D;
    float* Ob = Out + (size_t)bh * S * D;
    const float qscale = 0.125f * 1.44269504f;
    const int kr = tid >> 2;
    const int kc = (tid & 3) * 16;
    const int vd0   = (tid & 15) * 4;
    const int vkey0 = (tid >> 4) * 4;
    const float* kSrc = Kb + (size_t)kr * D + kc;
    const float* vSrc = Vb + (size_t)vkey0 * D + vd0;
    floatx4 kpre[4], vpre[4];
#pragma unroll
    for (int i = 0; i < 4; ++i) kpre[i] = *(const floatx4*)(kSrc + i*4);
#pragma unroll
    for (int r = 0; r < 4; ++r) vpre[r] = *(const floatx4*)(vSrc + (size_t)r*D);
    int pb = 0;
#pragma unroll 1
    for (int seg = 0; seg < 2; ++seg){
        const int qt  = seg ? (31 - qp) : qp;
        const int nkb = qt + 1;
        const int r0  = qt * 64 + wave * 16;
        short8 qa[2];
        {
            const float* qptr = Qb + (size_t)(r0 + l16) * D + quad * 8;
#pragma unroll
            for (int kt = 0; kt < 2; ++kt){
                floatx4 f0 = *(const floatx4*)(qptr + kt*32);
                floatx4 f1 = *(const floatx4*)(qptr + kt*32 + 4);
                short8 v;
                v[0]=f2bf(f0.x*qscale); v[1]=f2bf(f0.y*qscale);
                v[2]=f2bf(f0.z*qscale); v[3]=f2bf(f0.w*qscale);
                v[4]=f2bf(f1.x*qscale); v[5]=f2bf(f1.y*qscale);
                v[6]=f2bf(f1.z*qscale); v[7]=f2bf(f1.w*qscale);
                qa[kt] = v;
            }
        }
        float mrow = -1e30f, lsum = 0.0f;
        floatx4 Oacc[4];
#pragma unroll
        for (int dt = 0; dt < 4; ++dt) Oacc[dt] = (floatx4){0.f,0.f,0.f,0.f};
#pragma unroll 1
        for (int kb = 0; kb < nkb; ++kb){
            const int n0 = kb * 64;
            {
                short8 w0, w1;
                w0[0]=f2bf(kpre[0].x); w0[1]=f2bf(kpre[0].y); w0[2]=f2bf(kpre[0].z); w0[3]=f2bf(kpre[0].w);
                w0[4]=f2bf(kpre[1].x); w0[5]=f2bf(kpre[1].y); w0[6]=f2bf(kpre[1].z); w0[7]=f2bf(kpre[1].w);
                w1[0]=f2bf(kpre[2].x); w1[1]=f2bf(kpre[2].y); w1[2]=f2bf(kpre[2].z); w1[3]=f2bf(kpre[2].w);
                w1[4]=f2bf(kpre[3].x); w1[5]=f2bf(kpre[3].y); w1[6]=f2bf(kpre[3].z); w1[7]=f2bf(kpre[3].w);
                *(short8*)&sK[pb][kr * KSTR + kc]     = w0;
                *(short8*)&sK[pb][kr * KSTR + kc + 8] = w1;
#pragma unroll
                for (int j = 0; j < 4; ++j){
                    short4v sj;
                    sj[0]=f2bf(vpre[0][j]); sj[1]=f2bf(vpre[1][j]);
                    sj[2]=f2bf(vpre[2][j]); sj[3]=f2bf(vpre[3][j]);
                    *(short4v*)&sVt[pb][(vd0 + j) * VSTR + vkey0] = sj;
                }
            }
            {
                const int n0n = (kb + 1 < nkb) ? (n0 + 64) : 0;
                const float* ks = kSrc + (size_t)n0n * D;
                const float* vs = vSrc + (size_t)n0n * D;
#pragma unroll
                for (int i = 0; i < 4; ++i) kpre[i] = *(const floatx4*)(ks + i*4);
#pragma unroll
                for (int r = 0; r < 4; ++r) vpre[r] = *(const floatx4*)(vs + (size_t)r*D);
            }
            __syncthreads();
            const int lastT = min(3, (r0 + 15 - n0) >> 4);
            float p[4][4];
            float mx = -1e30f;
#pragma unroll
            for (int t = 0; t < 4; ++t){
#pragma unroll
                for (int r = 0; r < 4; ++r) p[t][r] = 0.0f;
                if (t > lastT) continue;
                const short8 kf0 = *(const short8*)&sK[pb][(t*16 + l16) * KSTR + quad*8];
                const short8 kf1 = *(const short8*)&sK[pb][(t*16 + l16) * KSTR + 32 + quad*8];
                floatx4 acc = (floatx4){0.f,0.f,0.f,0.f};
                acc = __builtin_amdgcn_mfma_f32_16x16x32_bf16(kf0, qa[0], acc, 0,0,0);
                acc = __builtin_amdgcn_mfma_f32_16x16x32_bf16(kf1, qa[1], acc, 0,0,0);
                if (n0 + t*16 + 15 > r0){
                    const int keyb = n0 + t*16 + quad*4;
                    const int qrow = r0 + l16;
#pragma unroll
                    for (int r = 0; r < 4; ++r)
                        acc[r] = (keyb + r <= qrow) ? acc[r] : -1e9f;
                }
#pragma unroll
                for (int r = 0; r < 4; ++r){ p[t][r] = acc[r]; mx = fmaxf(mx, acc[r]); }
            }
            mx = fmaxf(mx, __shfl_xor(mx, 16, 64));
            mx = fmaxf(mx, __shfl_xor(mx, 32, 64));
            const float mn = fmaxf(mrow, mx);
            const float al = fast_exp2(mrow - mn);
            mrow = mn;
            float rs = 0.0f;
#pragma unroll
            for (int t = 0; t < 4; ++t){
                if (t > lastT) continue;
#pragma unroll
                for (int r = 0; r < 4; ++r){
                    p[t][r] = fast_exp2(p[t][r] - mn);
                    rs += p[t][r];
                }
            }
            rs += __shfl_xor(rs, 16, 64);
            rs += __shfl_xor(rs, 32, 64);
            lsum = lsum * al + rs;
#pragma unroll
            for (int dt = 0; dt < 4; ++dt)
#pragma unroll
                for (int r = 0; r < 4; ++r) Oacc[dt][r] *= al;
            unsigned pk[4][2];
#pragma unroll
            for (int t = 0; t < 4; ++t)
#pragma unroll
                for (int h = 0; h < 2; ++h){
                    unsigned lo = __builtin_bit_cast(unsigned, p[t][2*h]);
                    unsigned hi = __builtin_bit_cast(unsigned, p[t][2*h+1]);
                    pk[t][h] = (lo >> 16) | (hi & 0xFFFF0000u);
                }
            const int addr_lo = (l16 + ((quad & 1) << 5)) << 2;
            const int addr_hi = addr_lo + 64;
            const bool hiQ = quad >= 2;
#pragma unroll
            for (int c = 0; c < 2; ++c){
                if (2*c > lastT) continue;
                const int ta = 2*c, tb = 2*c + 1;
                int a0 = __builtin_amdgcn_ds_bpermute(addr_lo, (int)pk[ta][0]);
                int b0 = __builtin_amdgcn_ds_bpermute(addr_lo, (int)pk[tb][0]);
                int a1 = __builtin_amdgcn_ds_bpermute(addr_lo, (int)pk[ta][1]);
                int b1 = __builtin_amdgcn_ds_bpermute(addr_lo, (int)pk[tb][1]);
                int a2 = __builtin_amdgcn_ds_bpermute(addr_hi, (int)pk[ta][0]);
                int b2 = __builtin_amdgcn_ds_bpermute(addr_hi, (int)pk[tb][0]);
                int a3 = __builtin_amdgcn_ds_bpermute(addr_hi, (int)pk[ta][1]);
                int b3 = __builtin_amdgcn_ds_bpermute(addr_hi, (int)pk[tb][1]);
                union { intx4 i4; short8 s8; } bf;
                bf.i4[0] = hiQ ? b0 : a0;
                bf.i4[1] = hiQ ? b1 : a1;
                bf.i4[2] = hiQ ? b2 : a2;
                bf.i4[3] = hiQ ? b3 : a3;
#pragma unroll
                for (int dt = 0; dt < 4; ++dt){
                    const short8 vf = *(const short8*)&sVt[pb][(dt*16 + l16) * VSTR + c*32 + quad*8];
                    Oacc[dt] = __builtin_amdgcn_mfma_f32_16x16x32_bf16(vf, bf.s8, Oacc[dt], 0,0,0);
                }
            }
            pb ^= 1;
        }
        const float inv = 1.0f / lsum;
        float* op = Ob + (size_t)(r0 + l16) * D + quad * 4;
#pragma unroll
        for (int dt = 0; dt < 4; ++dt){
            floatx4 o;
#pragma unroll
            for (int r = 0; r < 4; ++r) o[r] = Oacc[dt][r] * inv;
            *(floatx4*)(op + dt*16) = o;
        }
    }
}

extern "C" void kernel_launch(void* const* d_in, const int* in_sizes, int n_in,
                              void* d_out, int out_size, void* d_ws, size_t ws_size,
                              hipStream_t stream) {
    const float* q = (const float*)d_in[0];
    const float* k = (const float*)d_in[1];
    const float* v = (const float*)d_in[2];
    // d_in[3] = causal_mask: ignored (causality computed analytically)
    float* out = (float*)d_out;
    if (ws_size >= WS_NEEDED){
        short* Kf = (short*)d_ws;
        short* Vf = Kf + TENSOR_SH;
        hipLaunchKernelGGL(prepack_kernel, dim3(1024), dim3(256), 0, stream, k, v, Kf, Vf);
        hipLaunchKernelGGL(fa_fwd_kernel, dim3(1024), dim3(256), 0, stream, q, Kf, Vf, out);
    } else {
        hipLaunchKernelGGL(fa_fwd_fallback, dim3(512), dim3(256), 0, stream, q, k, v, out);
    }
}